// Round 3
// baseline (400.003 us; speedup 1.0000x reference)
//
#include <hip/hip_runtime.h>
#include <math.h>

#define NB 36

// f64 reference atan for u in [0,1]: octant reduce + fdlibm 11-coeff minimax
// (validated rounds 1-2). INIT KERNEL ONLY -- cost irrelevant.
__device__ __forceinline__ double atan_ref64(double u) {
  bool hi = u > 0.41421356237309503;
  double q = hi ? (u - 1.0) / (u + 1.0) : u;
  double t = q * q;
  double R =      1.62858201153657823623e-02;
  R = fma(R, t, -3.65315727442169155270e-02);
  R = fma(R, t,  4.97687799461593236017e-02);
  R = fma(R, t, -5.83357013379057348645e-02);
  R = fma(R, t,  6.66107313738753120669e-02);
  R = fma(R, t, -7.69187620504482999495e-02);
  R = fma(R, t,  9.09088713343650656196e-02);
  R = fma(R, t, -1.11111104054623557880e-01);
  R = fma(R, t,  1.42857142725034663711e-01);
  R = fma(R, t, -1.99999999998764832476e-01);
  R = fma(R, t,  3.33333333333329318027e-01);
  double h = t * R;
  double a = fma(-h, q, q);
  return hi ? (0.7853981633974483 + a) : a;
}

// 4-way folded dd table: T[j][k] = C[j] + s[j]*atan(k/128), j = swp + 2*gxneg.
//   j=0 (swp0,gx+): C=0,    s=+1      j=1 (swp1,gx+): C=pi/2, s=-1
//   j=2 (swp0,gx-): C=pi,   s=-1      j=3 (swp1,gx-): C=pi/2, s=+1
// Stored as f32 hi/lo pair (dd): represents theta to ~2^-46 abs.
__device__ float2 g_atab[512];

__global__ void init_atab(void) {
  int t = threadIdx.x;               // 512 threads
  int j = t >> 7, k = t & 127;
  double th = atan_ref64((double)k * 0.0078125);
  double C = (j == 0) ? 0.0 : (j == 2) ? 3.141592653589793 : 1.5707963267948966;
  double s = (j == 0 || j == 3) ? 1.0 : -1.0;
  double v = C + s * th;
  float hi = (float)v;
  float lo = (float)(v - (double)hi);
  g_atab[t] = make_float2(hi, lo);
}

// All-f32 double-float atan2, total abs err ~2^-44 rad (validated family:
// s1 = ori+PI absorbs sub-2^-23 noise; expected b0 flips ~1e-4 over 67M px).
//  - k = round(128*mn/mx) via HW rcp (either neighbor valid), c = k/128
//  - num = mn - c*mx exact dd {nh,-pl}: nh EXACT (Sterbenz: c*mx in
//    [mn/2,2mn] for k>=1; k=0 -> ph=0), pl = fma residual (exact)
//  - den = mx + c*mn as dd {dh,dl} via exact Fast2Sum (mx >= c*mn)
//  - q = num/den as dd {qh,ql}: rcp(dh) + fma correction series, rel ~2^-45.5
//  - atan(q) = q - q*t*(1/3 - t*(1/5 - t/7)), |q|<=2^-7: tail f32-safe
//  - theta = T_dd + s*(q - cube): sign s folded into nh/pl sign bits;
//    Fast2Sum(T.hi, qh) exact (T.hi >= |qh| whenever T.hi != 0)
__device__ __forceinline__ float atan2f_dd(float gyf, float gxf,
                                           const float2* __restrict__ atab) {
  float axf = fabsf(gxf);
  float ayf = fabsf(gyf);
  float mnf = fminf(axf, ayf);
  float mxf = fmaxf(axf, ayf);
  float mxg = (mxf == 0.0f) ? 1.0f : mxf;   // gx=gy=0 -> q=0, T[j][0]
  const bool swp   = ayf > axf;
  const bool gxneg = gxf < 0.0f;
  const int  j     = (swp ? 1 : 0) | (gxneg ? 2 : 0);
  const int  smask = (swp != gxneg) ? 0x80000000 : 0;   // s[j] < 0

  float r0 = __builtin_amdgcn_rcpf(mxg);
  float cm = fminf(rintf((mnf * r0) * 128.0f), 127.0f); // k in [0,127]
  int   k  = (int)cm;
  float cf = cm * 0.0078125f;                           // exact k/128

  // num dd (sign-folded)
  float ph = cf * mxg;
  float pl = fmaf(cf, mxg, -ph);            // exact residual
  float nh = mnf - ph;                      // EXACT (Sterbenz / ph==0)
  nh = __int_as_float(__float_as_int(nh) ^ smask);
  pl = __int_as_float(__float_as_int(pl) ^ smask);

  // den dd
  float ph2 = cf * mnf;
  float pl2 = fmaf(cf, mnf, -ph2);          // exact residual
  float dh  = mxg + ph2;
  float dl  = ((mxg - dh) + ph2) + pl2;     // Fast2Sum exact + pl2 fold

  // q dd = (nh - pl) / (dh + dl)
  float rA  = __builtin_amdgcn_rcpf(dh);
  float e   = fmaf(-dh, rA, 1.0f);
  float em  = fmaf(-dl, rA, e);             // 1 - den*rA to ~2^-47
  float qh  = nh * rA;
  float plo = fmaf(nh, rA, -qh);            // exact residual
  float ql  = fmaf(qh, em, plo);
  ql = fmaf(-pl, rA, ql);

  // cube/quintic correction on qs = qh+ql (keeps cube err ~2^-45)
  float qs = qh + ql;
  float t  = qs * qs;                       // <= 2^-14
  float S  = fmaf(-t, 0.14285715f, 0.2f);
  float Rp = fmaf(-t, S, 0.33333334f);
  float cu = qs * (t * Rp);                 // <= 2^-22.6

  float2 T = atab[(j << 7) | k];
  float hh = T.x + qh;
  float e1 = (T.x - hh) + qh;               // Fast2Sum residual (exact)
  float lo = ((ql - cu) + T.y) + e1;
  float f  = hh + lo;                       // single rounding of theta_dd
  return copysignf(f, gyf);
}

// Per-pixel pipeline (unchanged validated structure): b0/wo1 via the exact
// s1/ob chain (Markstein CR f32 division); mag via fma-fold + raw v_sqrt.
#define PX(L, R, UP, DN, G) do {                                    \
    float gx_ = 0.5f * ((L) - (R));                                 \
    float gy_ = 0.5f * ((UP) - (DN));                               \
    float m2_ = fmaf(gy_, gy_, fmaf(gx_, gx_, 1e-10f));             \
    float mag_ = __builtin_amdgcn_sqrtf(m2_) * (G);                 \
    float ori_ = atan2f_dd(gy_, gx_, atabl);                        \
    float s1_ = ori_ + PI_F;                                        \
    float d2_ = 36.0f * s1_;                                        \
    float q0_ = d2_ * C_INV_TPI;      /* Markstein CR f32 division */ \
    float rm_ = fmaf(-TPI_F, q0_, d2_);                             \
    float ob_ = fmaf(rm_, C_INV_TPI, q0_);                          \
    float fo_ = floorf(ob_);                                        \
    float wo1_ = ob_ - fo_;                                         \
    int b0_ = (int)fo_;                                             \
    if (b0_ >= NB) b0_ -= NB;                                       \
    h[b0_] += fmaf(-wo1_, mag_, mag_);                              \
  } while (0)

#define QUAD(cq, uq, dq, gq, LV, RV) do {                           \
    PX(LV,   cq.y, uq.x, dq.x, gq.x);                               \
    PX(cq.x, cq.z, uq.y, dq.y, gq.y);                               \
    PX(cq.y, cq.w, uq.z, dq.z, gq.z);                               \
    PX(cq.z, RV,   uq.w, dq.w, gq.w);                               \
  } while (0)

#define UP1(v) __shfl_up((v), 1, 32)
#define DN1(v) __shfl_down((v), 1, 32)

// One WAVE per 32x32 patch; per-lane 36-bin LDS hist (stride 36: epilogue
// reads are 2-way/broadcast -> free; RMW conflict class unchanged vs 37);
// run-order per-bin reduction (validated regrouping).  LDS total:
// hist 36864 + table 4096 = 40960 B exactly -> 4 blocks/CU.
__global__ __launch_bounds__(256, 4) void orient_kernel(
    const float* __restrict__ x,
    const float* __restrict__ gk,
    float* __restrict__ out)
{
#pragma clang fp contract(off)
  __shared__ float  hist[256 * 36];   // 36864 B
  __shared__ float2 atabl[512];       //  4096 B

  const int t    = threadIdx.x;
  const int lane = t & 63;
  const int row  = lane & 31;
  const int half = lane >> 5;
  const int p    = (blockIdx.x * 256 + t) >> 6;   // global wave id == patch

  const float PI_F  = 3.14159265358979323846f;   // 0x40490FDB
  const float TPI_F = 6.28318530717958647692f;   // 0x40C90FDB
  const float C_INV_TPI = (float)(1.0 / (double)6.28318530717958647692f);

  atabl[t]       = g_atab[t];
  atabl[t + 256] = g_atab[t + 256];

  float* __restrict__ h = &hist[t * 36];
  #pragma unroll
  for (int b = 0; b < NB; ++b) h[b] = 0.0f;

  __syncthreads();                   // publish atabl to all 4 waves

  const float4* __restrict__ xv =
      (const float4*)(x + (size_t)p * 1024 + (row * 32 + half * 16));
  const float4* __restrict__ gv = (const float4*)(gk + (row * 32 + half * 16));
  float4 c0 = xv[0], c1 = xv[1], c2 = xv[2], c3 = xv[3];
  float4 g0 = gv[0], g1 = gv[1], g2 = gv[2], g3 = gv[3];

  float4 u0, u1, u2, u3, d0, d1, d2, d3;
  u0.x=UP1(c0.x); u0.y=UP1(c0.y); u0.z=UP1(c0.z); u0.w=UP1(c0.w);
  u1.x=UP1(c1.x); u1.y=UP1(c1.y); u1.z=UP1(c1.z); u1.w=UP1(c1.w);
  u2.x=UP1(c2.x); u2.y=UP1(c2.y); u2.z=UP1(c2.z); u2.w=UP1(c2.w);
  u3.x=UP1(c3.x); u3.y=UP1(c3.y); u3.z=UP1(c3.z); u3.w=UP1(c3.w);
  d0.x=DN1(c0.x); d0.y=DN1(c0.y); d0.z=DN1(c0.z); d0.w=DN1(c0.w);
  d1.x=DN1(c1.x); d1.y=DN1(c1.y); d1.z=DN1(c1.z); d1.w=DN1(c1.w);
  d2.x=DN1(c2.x); d2.y=DN1(c2.y); d2.z=DN1(c2.z); d2.w=DN1(c2.w);
  d3.x=DN1(c3.x); d3.y=DN1(c3.y); d3.z=DN1(c3.z); d3.w=DN1(c3.w);

  float send = half ? c0.x : c3.w;
  float recv = __shfl_xor(send, 32, 64);
  float LB = half ? recv : c0.x;    // left neighbor of this chunk's col 0
  float RB = half ? c3.w : recv;    // right neighbor of this chunk's col 15

  QUAD(c0, u0, d0, g0, LB,   c1.x);
  QUAD(c1, u1, d1, g1, c0.w, c2.x);
  QUAD(c2, u2, d2, g2, c1.w, c3.x);
  QUAD(c3, u3, d3, g3, c2.w, RB);

  __builtin_amdgcn_wave_barrier();   // keep phase order; DS in-order per wave

  // per-bin reduction over lane-hists in pixel-run order:
  // run k covers pixels [k*16, k*16+16) -> owning lane = (k>>1) + 32*(k&1)
  const float* __restrict__ hw = &hist[(t >> 6) * 2304];
  const int bb = (lane < NB) ? lane : NB - 1;     // clamp; masked later
  float s = 0.0f;
  #pragma unroll
  for (int k = 0; k < 64; ++k) {
    const int l = (k >> 1) + ((k & 1) << 5);
    s += hw[l * 36 + bb];
  }

  // zero-padded [0.33,0.34,0.33] smooth + 64-lane first-index argmax
  float ll = __shfl(s, lane - 1);
  float rr = __shfl(s, lane + 1);
  float v; int idx;
  if (lane < NB) {
    float sl = (lane > 0)      ? ll : 0.0f;
    float sr = (lane < NB - 1) ? rr : 0.0f;
    v = (0.33f * sl + 0.34f * s) + 0.33f * sr;    // ref association
    idx = lane;
  } else {
    v = -INFINITY; idx = 1 << 20;
  }
  #pragma unroll
  for (int off = 32; off > 0; off >>= 1) {
    float v2 = __shfl_xor(v, off, 64);
    int   i2 = __shfl_xor(idx, off, 64);
    if (v2 > v || (v2 == v && i2 < idx)) { v = v2; idx = i2; }
  }
  if (lane == 0) {
    out[p] = -((TPI_F * (float)idx) / 36.0f - PI_F);
  }
}

extern "C" void kernel_launch(void* const* d_in, const int* in_sizes, int n_in,
                              void* d_out, int out_size, void* d_ws, size_t ws_size,
                              hipStream_t stream) {
  const float* x  = (const float*)d_in[0];
  const float* gk = (const float*)d_in[1];
  float* out = (float*)d_out;
  const int B = in_sizes[0] / 1024;        // 65536 patches
  init_atab<<<1, 512, 0, stream>>>();
  orient_kernel<<<B / 4, 256, 0, stream>>>(x, gk, out);
}